// Round 13
// baseline (519.884 us; speedup 1.0000x reference)
//
#include <hip/hip_runtime.h>

#define N_NODES 100000
#define N_EDGES 500000
#define N_GRAPHS 64
#define IN_DIM 512
#define HID 256
#define NREL 16

using short8 = __attribute__((ext_vector_type(8))) short;
using f32x4  = __attribute__((ext_vector_type(4))) float;

__device__ __forceinline__ unsigned short f2bf(float f) {
    union { float f; unsigned u; } v; v.f = f;
    unsigned u = v.u;
    unsigned r = u + 0x7FFF + ((u >> 16) & 1);
    return (unsigned short)(r >> 16);
}
__device__ __forceinline__ float bf2f(unsigned short h) {
    union { unsigned u; float f; } v; v.u = ((unsigned)h) << 16;
    return v.f;
}
// packed fp32->bf16 RNE (native, gfx950)
__device__ __forceinline__ unsigned cvtpk(float lo, float hi) {
    unsigned r;
    asm("v_cvt_pk_bf16_f32 %0, %1, %2" : "=v"(r) : "v"(lo), "v"(hi));
    return r;
}

__device__ __forceinline__ void gload_lds16(const unsigned short* g, unsigned short* l) {
    __builtin_amdgcn_global_load_lds(
        (const __attribute__((address_space(1))) void*)(g),
        (__attribute__((address_space(3))) void*)(l), 16, 0, 0);
}
__device__ __forceinline__ void gload_lds16f(const float* g, float* l) {
    __builtin_amdgcn_global_load_lds(
        (const __attribute__((address_space(1))) void*)(g),
        (__attribute__((address_space(3))) void*)(l), 16, 0, 0);
}

// ---------------- weight prep (fused): Wt[n][k] = bf16(n<256 ? Wrel[k][n] : Wroot[k][n-256])
// grid = dim3(8, 8, 3); z selects layer; layers 1,2 use only blockIdx.x < 4 (K=256).
__global__ void k_makeWtAll(const float* __restrict__ Wrel0, const float* __restrict__ Wroot0,
                            const float* __restrict__ Wrel1, const float* __restrict__ Wroot1,
                            const float* __restrict__ Wrel2, const float* __restrict__ Wroot2,
                            unsigned short* __restrict__ Wt0, unsigned short* __restrict__ Wt1,
                            unsigned short* __restrict__ Wt2) {
    __shared__ float t[64][65];
    int z = blockIdx.z;
    int K = (z == 0) ? 512 : 256;
    if (blockIdx.x * 64 >= K) return;
    const float* Wrel  = (z == 0) ? Wrel0  : (z == 1) ? Wrel1  : Wrel2;
    const float* Wroot = (z == 0) ? Wroot0 : (z == 1) ? Wroot1 : Wroot2;
    unsigned short* Wt = (z == 0) ? Wt0    : (z == 1) ? Wt1    : Wt2;
    int tid = threadIdx.x;
    int tk = blockIdx.x * 64, tn = blockIdx.y * 64;
    const float* Wsrc = (tn < 256) ? Wrel : Wroot;
    int col0 = tn & 255;
    #pragma unroll
    for (int r = 0; r < 16; ++r) {
        int kl = r * 4 + (tid >> 6);
        int nl = tid & 63;
        t[kl][nl] = Wsrc[(size_t)(tk + kl) * 256 + col0 + nl];
    }
    __syncthreads();
    #pragma unroll
    for (int r = 0; r < 16; ++r) {
        int nl = r * 4 + (tid >> 6);
        int kl = tid & 63;
        Wt[(size_t)(tn + nl) * K + tk + kl] = f2bf(t[kl][nl]);
    }
}

// We2T[r][k], r<32, k<256
__global__ void k_makeWe2T(const float* __restrict__ We, unsigned short* __restrict__ We2T) {
    int idx = blockIdx.x * 256 + threadIdx.x;
    if (idx >= 32 * 256) return;
    int r = idx >> 8, k = idx & 255;
    float v = (r < 16) ? We[k * NREL + r] : We[(256 + k) * NREL + (r - 16)];
    We2T[idx] = f2bf(v);
}

// ---------------- CSR build ----------------
__global__ void k_hist(const int* __restrict__ dstArr, int* __restrict__ counts) {
    int i = blockIdx.x * 256 + threadIdx.x;
    if (i < N_EDGES) atomicAdd(&counts[dstArr[i]], 1);
}

__global__ void k_scanA(const int* __restrict__ counts, int* __restrict__ bsum) {
    __shared__ int ws[4];
    int i = blockIdx.x * 256 + threadIdx.x;
    int v = (i < N_NODES) ? counts[i] : 0;
    for (int o = 32; o; o >>= 1) v += __shfl_down(v, o, 64);
    if ((threadIdx.x & 63) == 0) ws[threadIdx.x >> 6] = v;
    __syncthreads();
    if (threadIdx.x == 0) bsum[blockIdx.x] = ws[0] + ws[1] + ws[2] + ws[3];
}

__global__ void k_scanB(int* __restrict__ bsum, int nb) {
    __shared__ int buf[512];
    int t = threadIdx.x;
    for (int i = t; i < nb; i += 256) buf[i] = bsum[i];
    __syncthreads();
    if (t == 0) { int s = 0; for (int i = 0; i < nb; ++i) { int x = buf[i]; buf[i] = s; s += x; } }
    __syncthreads();
    for (int i = t; i < nb; i += 256) bsum[i] = buf[i];
}

__global__ void k_scanC(const int* __restrict__ counts, const int* __restrict__ bsum,
                        int* __restrict__ offsets, int* __restrict__ cur) {
    __shared__ int ws[4];
    int i = blockIdx.x * 256 + threadIdx.x;
    int lane = threadIdx.x & 63, wid = threadIdx.x >> 6;
    int v = (i < N_NODES) ? counts[i] : 0;
    int x = v;
    for (int o = 1; o < 64; o <<= 1) { int u = __shfl_up(x, o, 64); if (lane >= o) x += u; }
    if (lane == 63) ws[wid] = x;
    __syncthreads();
    if (threadIdx.x == 0) { int s = 0; for (int t = 0; t < 4; ++t) { int tt = ws[t]; ws[t] = s; s += tt; } }
    __syncthreads();
    x += ws[wid];
    x += bsum[blockIdx.x];
    if (i < N_NODES) { offsets[i + 1] = x; cur[i] = x - v; }
    if (i == 0) offsets[0] = 0;
}

__global__ void k_fill(const int* __restrict__ srcArr, const int* __restrict__ dstArr,
                       int* __restrict__ cur, int* __restrict__ csr) {
    int i = blockIdx.x * 256 + threadIdx.x;
    if (i < N_EDGES) {
        int p = atomicAdd(&cur[dstArr[i]], 1);
        csr[p] = srcArr[i];
    }
}

// ---------------- GEMM (bf16 A): [Yrel|Yroot][M x 256] = A[M x K] @ Bt[512 x K]^T ----------
__global__ __launch_bounds__(256) void k_gemm(const unsigned short* __restrict__ A,
                                              const unsigned short* __restrict__ Bt,
                                              unsigned short* __restrict__ Yrel,
                                              unsigned short* __restrict__ Yroot,
                                              int M, int K) {
    __shared__ unsigned short lds[2 * 128 * 64];
    const int tid  = threadIdx.x;
    const int lane = tid & 63;
    const int w    = tid >> 6;
    const int wm   = w >> 1, wn = w & 1;

    int nwg  = gridDim.x;
    int orig = blockIdx.x;
    int q    = nwg >> 3;
    int id   = (orig & 7) * q + (orig >> 3);
    int bm0  = (id >> 2) * 128;
    int bn0  = (id & 3) * 128;

    f32x4 acc[4][4] = {};

    const int nkt = K >> 6;
    for (int kt = 0; kt < nkt; ++kt) {
        int k0 = kt << 6;
        #pragma unroll
        for (int it = 0; it < 4; ++it) {
            int c = (it << 8) + tid;
            int row = c >> 3, kcp = c & 7;
            int kcl = kcp ^ (row & 7);
            int gr = bm0 + row; gr = (gr < M) ? gr : (M - 1);
            gload_lds16(A + (size_t)gr * K + k0 + kcl * 8,
                        &lds[(size_t)((it << 8) + (w << 6)) * 8]);
        }
        #pragma unroll
        for (int it = 0; it < 4; ++it) {
            int c = (it << 8) + tid;
            int row = c >> 3, kcp = c & 7;
            int kcl = kcp ^ (row & 7);
            gload_lds16(Bt + (size_t)(bn0 + row) * K + k0 + kcl * 8,
                        &lds[128 * 64 + (size_t)((it << 8) + (w << 6)) * 8]);
        }
        __syncthreads();
        #pragma unroll
        for (int kk = 0; kk < 2; ++kk) {
            short8 af[4], bfr[4];
            #pragma unroll
            for (int m = 0; m < 4; ++m) {
                int row = wm * 64 + m * 16 + (lane & 15);
                int g = ((kk << 2) + (lane >> 4)) ^ (row & 7);
                af[m] = *(const short8*)&lds[row * 64 + g * 8];
            }
            #pragma unroll
            for (int n = 0; n < 4; ++n) {
                int row = wn * 64 + n * 16 + (lane & 15);
                int g = ((kk << 2) + (lane >> 4)) ^ (row & 7);
                bfr[n] = *(const short8*)&lds[128 * 64 + row * 64 + g * 8];
            }
            #pragma unroll
            for (int m = 0; m < 4; ++m)
                #pragma unroll
                for (int n = 0; n < 4; ++n)
                    acc[m][n] = __builtin_amdgcn_mfma_f32_16x16x32_bf16(af[m], bfr[n], acc[m][n], 0, 0, 0);
        }
        __syncthreads();
    }
    unsigned short* Cout = (bn0 < 256) ? Yrel : Yroot;
    int cb = bn0 & 255;
    #pragma unroll
    for (int m = 0; m < 4; ++m) {
        int row0 = bm0 + wm * 64 + m * 16 + ((lane >> 4) << 2);
        #pragma unroll
        for (int n = 0; n < 4; ++n) {
            int col = cb + wn * 64 + n * 16 + (lane & 15);
            #pragma unroll
            for (int i = 0; i < 4; ++i) {
                int r = row0 + i;
                if (r < M) Cout[(size_t)r * 256 + col] = f2bf(acc[m][n][i]);
            }
        }
    }
}

// ---------------- GEMM L0 (fp32 A, async DMA, cvt_pk on read) — BK=32 for occupancy --------
// LDS 24KB/block -> ~6 blocks/CU (was 48KB -> 2.4). Same 2-barrier structure; K-chunk
// accumulation order identical to BK=64 version (bit-identical output).
__global__ __launch_bounds__(256) void k_gemm0(const float* __restrict__ A,
                                               const unsigned short* __restrict__ Bt,
                                               unsigned short* __restrict__ Yrel,
                                               unsigned short* __restrict__ Yroot,
                                               int M) {
    constexpr int K = 512;
    __shared__ float ldsA[128 * 32];            // 16 KB
    __shared__ unsigned short ldsB[128 * 32];   // 8 KB
    const int tid  = threadIdx.x;
    const int lane = tid & 63;
    const int w    = tid >> 6;
    const int wm   = w >> 1, wn = w & 1;

    int nwg  = gridDim.x;
    int orig = blockIdx.x;
    int q    = nwg >> 3;
    int id   = (orig & 7) * q + (orig >> 3);
    int bm0  = (id >> 2) * 128;
    int bn0  = (id & 3) * 128;

    f32x4 acc[4][4] = {};

    const int nkt = K >> 5;   // 16
    for (int kt = 0; kt < nkt; ++kt) {
        int k0 = kt << 5;
        // stage A fp32 tile [128][32]: 1024 granules of 16B, 4/thread; swizzle over 8 slots
        #pragma unroll
        for (int it = 0; it < 4; ++it) {
            int gi = (it << 8) + tid;
            int row = gi >> 3, gp = gi & 7;
            int gs = gp ^ (row & 7);
            int gr = bm0 + row; gr = (gr < M) ? gr : (M - 1);
            gload_lds16f(A + (size_t)gr * K + k0 + gs * 4,
                         &ldsA[(size_t)((it << 8) + (w << 6)) * 4]);
        }
        // stage B bf16 tile [128][32]: 512 granules, 2/thread; swizzle over 4 slots
        #pragma unroll
        for (int it = 0; it < 2; ++it) {
            int gi = (it << 8) + tid;
            int row = gi >> 2, kcp = gi & 3;
            int kcl = kcp ^ ((row >> 1) & 3);
            gload_lds16(Bt + (size_t)(bn0 + row) * K + k0 + kcl * 8,
                        &ldsB[(size_t)((it << 8) + (w << 6)) * 8]);
        }
        __syncthreads();
        short8 af[4], bfr[4];
        #pragma unroll
        for (int m = 0; m < 4; ++m) {
            int row = wm * 64 + m * 16 + (lane & 15);
            int c = lane >> 4;                  // 8-float chunk 0..3
            int g0 = (2 * c) ^ (row & 7);
            int g1 = (2 * c + 1) ^ (row & 7);
            f32x4 fa = *(const f32x4*)&ldsA[row * 32 + g0 * 4];
            f32x4 fb = *(const f32x4*)&ldsA[row * 32 + g1 * 4];
            union { short8 s8; unsigned u[4]; } vv;
            vv.u[0] = cvtpk(fa[0], fa[1]);
            vv.u[1] = cvtpk(fa[2], fa[3]);
            vv.u[2] = cvtpk(fb[0], fb[1]);
            vv.u[3] = cvtpk(fb[2], fb[3]);
            af[m] = vv.s8;
        }
        #pragma unroll
        for (int n = 0; n < 4; ++n) {
            int row = wn * 64 + n * 16 + (lane & 15);
            int g = (lane >> 4) ^ ((row >> 1) & 3);
            bfr[n] = *(const short8*)&ldsB[row * 32 + g * 8];
        }
        #pragma unroll
        for (int m = 0; m < 4; ++m)
            #pragma unroll
            for (int n = 0; n < 4; ++n)
                acc[m][n] = __builtin_amdgcn_mfma_f32_16x16x32_bf16(af[m], bfr[n], acc[m][n], 0, 0, 0);
        __syncthreads();
    }
    unsigned short* Cout = (bn0 < 256) ? Yrel : Yroot;
    int cb = bn0 & 255;
    #pragma unroll
    for (int m = 0; m < 4; ++m) {
        int row0 = bm0 + wm * 64 + m * 16 + ((lane >> 4) << 2);
        #pragma unroll
        for (int n = 0; n < 4; ++n) {
            int col = cb + wn * 64 + n * 16 + (lane & 15);
            #pragma unroll
            for (int i = 0; i < 4; ++i) {
                int r = row0 + i;
                if (r < M) Cout[(size_t)r * 256 + col] = f2bf(acc[m][n][i]);
            }
        }
    }
}

// ---------------- fused aggregate + root + bias + ReLU -> bf16 (2 nodes/wave, short8) -------
__device__ __forceinline__ void acc8(float4& lo, float4& hi, short8 v) {
    lo.x += bf2f((unsigned short)v[0]); lo.y += bf2f((unsigned short)v[1]);
    lo.z += bf2f((unsigned short)v[2]); lo.w += bf2f((unsigned short)v[3]);
    hi.x += bf2f((unsigned short)v[4]); hi.y += bf2f((unsigned short)v[5]);
    hi.z += bf2f((unsigned short)v[6]); hi.w += bf2f((unsigned short)v[7]);
}

__global__ void k_combine(const unsigned short* __restrict__ yrel,
                          const unsigned short* __restrict__ yroot,
                          const int* __restrict__ offs,
                          const int* __restrict__ csr, const float* __restrict__ bias,
                          unsigned short* __restrict__ xout) {
    int node = blockIdx.x * 8 + (threadIdx.x >> 5);
    if (node >= N_NODES) return;
    int l32 = threadIdx.x & 31;
    int d = l32 * 8;
    int j0 = offs[node], j1 = offs[node + 1];
    float4 a0l = {0,0,0,0}, a0h = {0,0,0,0};
    float4 a1l = {0,0,0,0}, a1h = {0,0,0,0};
    float4 a2l = {0,0,0,0}, a2h = {0,0,0,0};
    float4 a3l = {0,0,0,0}, a3h = {0,0,0,0};
    int j = j0;
    for (; j + 4 <= j1; j += 4) {
        int s0 = csr[j], s1 = csr[j + 1], s2 = csr[j + 2], s3 = csr[j + 3];
        short8 v0 = *(const short8*)(yrel + (size_t)s0 * 256 + d);
        short8 v1 = *(const short8*)(yrel + (size_t)s1 * 256 + d);
        short8 v2 = *(const short8*)(yrel + (size_t)s2 * 256 + d);
        short8 v3 = *(const short8*)(yrel + (size_t)s3 * 256 + d);
        acc8(a0l, a0h, v0); acc8(a1l, a1h, v1);
        acc8(a2l, a2h, v2); acc8(a3l, a3h, v3);
    }
    for (; j < j1; ++j) {
        int s = csr[j];
        acc8(a0l, a0h, *(const short8*)(yrel + (size_t)s * 256 + d));
    }
    a0l.x += a1l.x + a2l.x + a3l.x;  a0l.y += a1l.y + a2l.y + a3l.y;
    a0l.z += a1l.z + a2l.z + a3l.z;  a0l.w += a1l.w + a2l.w + a3l.w;
    a0h.x += a1h.x + a2h.x + a3h.x;  a0h.y += a1h.y + a2h.y + a3h.y;
    a0h.z += a1h.z + a2h.z + a3h.z;  a0h.w += a1h.w + a2h.w + a3h.w;
    short8 rr = *(const short8*)(yroot + (size_t)node * 256 + d);
    float4 bl = *(const float4*)(bias + d);
    float4 bh = *(const float4*)(bias + d + 4);
    short8 pk;
    pk[0] = (short)f2bf(fmaxf(a0l.x + bf2f((unsigned short)rr[0]) + bl.x, 0.f));
    pk[1] = (short)f2bf(fmaxf(a0l.y + bf2f((unsigned short)rr[1]) + bl.y, 0.f));
    pk[2] = (short)f2bf(fmaxf(a0l.z + bf2f((unsigned short)rr[2]) + bl.z, 0.f));
    pk[3] = (short)f2bf(fmaxf(a0l.w + bf2f((unsigned short)rr[3]) + bl.w, 0.f));
    pk[4] = (short)f2bf(fmaxf(a0h.x + bf2f((unsigned short)rr[4]) + bh.x, 0.f));
    pk[5] = (short)f2bf(fmaxf(a0h.y + bf2f((unsigned short)rr[5]) + bh.y, 0.f));
    pk[6] = (short)f2bf(fmaxf(a0h.z + bf2f((unsigned short)rr[6]) + bh.z, 0.f));
    pk[7] = (short)f2bf(fmaxf(a0h.w + bf2f((unsigned short)rr[7]) + bh.w, 0.f));
    *(short8*)(xout + (size_t)node * HID + d) = pk;
}

// ---------------- edge head, stage 1: P[N x 32] = x3 @ We2T^T (fp32 out) ----------------
__global__ void k_proj(const unsigned short* __restrict__ x,
                       const unsigned short* __restrict__ We2T,
                       float* __restrict__ P) {
    int lane = threadIdx.x & 63;
    int g = blockIdx.x * 4 + (threadIdx.x >> 6);
    if (g * 16 >= N_NODES) return;
    int n0 = g * 16;
    short8 bfr[2][8];
    #pragma unroll
    for (int cg = 0; cg < 2; ++cg)
        #pragma unroll
        for (int ks = 0; ks < 8; ++ks)
            bfr[cg][ks] = *(const short8*)&We2T[(size_t)(cg * 16 + (lane & 15)) * 256 + ks * 32 + ((lane >> 4) << 3)];
    f32x4 acc[2] = {};
    const size_t rb = (size_t)(n0 + (lane & 15)) * 256 + ((lane >> 4) << 3);
    #pragma unroll
    for (int ks = 0; ks < 8; ++ks) {
        short8 af = *(const short8*)&x[rb + ks * 32];
        acc[0] = __builtin_amdgcn_mfma_f32_16x16x32_bf16(af, bfr[0][ks], acc[0], 0, 0, 0);
        acc[1] = __builtin_amdgcn_mfma_f32_16x16x32_bf16(af, bfr[1][ks], acc[1], 0, 0, 0);
    }
    #pragma unroll
    for (int cg = 0; cg < 2; ++cg) {
        #pragma unroll
        for (int i = 0; i < 4; ++i) {
            int n = n0 + ((lane >> 4) << 2) + i;
            P[(size_t)n * 32 + cg * 16 + (lane & 15)] = acc[cg][i];
        }
    }
}

// ---------------- edge head, stage 2 ----------
__global__ void k_edge_add(const float* __restrict__ P,
                           const int* __restrict__ srcArr, const int* __restrict__ dstArr,
                           const float* __restrict__ b_edge, float* __restrict__ out) {
    int e = blockIdx.x * 256 + threadIdx.x;
    if (e >= N_EDGES) return;
    int s = srcArr[e], d = dstArr[e];
    const float4* ps = (const float4*)(P + (size_t)s * 32);
    const float4* pd = (const float4*)(P + (size_t)d * 32 + 16);
    const float4* bb = (const float4*)b_edge;
    float4* po = (float4*)(out + (size_t)e * 16);
    #pragma unroll
    for (int i = 0; i < 4; ++i) {
        float4 a = ps[i], b = pd[i], c = bb[i];
        float4 rr;
        rr.x = a.x + b.x + c.x; rr.y = a.y + b.y + c.y;
        rr.z = a.z + b.z + c.z; rr.w = a.w + b.w + c.w;
        po[i] = rr;
    }
}

// ---------------- mean pool ----------------
__global__ void k_pool_sum(const unsigned short* __restrict__ x, const int* __restrict__ batch,
                           float* __restrict__ sums) {
    const int CH = 32;
    int w = threadIdx.x >> 6, lane = threadIdx.x & 63;
    int n0 = blockIdx.x * (4 * CH) + w * CH;
    if (n0 >= N_NODES) return;
    int n1 = n0 + CH; if (n1 > N_NODES) n1 = N_NODES;
    int d = lane * 4;
    float a0 = 0.f, a1 = 0.f, a2 = 0.f, a3 = 0.f;
    int gcur = batch[n0];
    for (int n = n0; n < n1; ++n) {
        int g = batch[n];
        if (g != gcur) {
            float* p = &sums[gcur * HID + d];
            atomicAdd(p + 0, a0); atomicAdd(p + 1, a1);
            atomicAdd(p + 2, a2); atomicAdd(p + 3, a3);
            a0 = a1 = a2 = a3 = 0.f; gcur = g;
        }
        ushort4 v = *(const ushort4*)&x[(size_t)n * HID + d];
        a0 += bf2f(v.x); a1 += bf2f(v.y); a2 += bf2f(v.z); a3 += bf2f(v.w);
    }
    float* p = &sums[gcur * HID + d];
    atomicAdd(p + 0, a0); atomicAdd(p + 1, a1);
    atomicAdd(p + 2, a2); atomicAdd(p + 3, a3);
}

__device__ __forceinline__ int lowerBound(const int* a, int n, int key) {
    int lo = 0, hi = n;
    while (lo < hi) { int mid = (lo + hi) >> 1; if (a[mid] < key) lo = mid + 1; else hi = mid; }
    return lo;
}

__global__ void k_pool_final(const float* __restrict__ sums, const int* __restrict__ batch,
                             float* __restrict__ out) {
    int g = blockIdx.x, d = threadIdx.x;
    int lo = lowerBound(batch, N_NODES, g);
    int hi = lowerBound(batch, N_NODES, g + 1);
    float cnt = (float)(hi - lo);
    out[(size_t)g * HID + d] = sums[g * HID + d] / fmaxf(cnt, 1.0f);
}

// ---------------- launcher ----------------
extern "C" void kernel_launch(void* const* d_in, const int* in_sizes, int n_in,
                              void* d_out, int out_size, void* d_ws, size_t ws_size,
                              hipStream_t stream) {
    const float* node_feats = (const float*)d_in[0];
    const int*   edge_index = (const int*)d_in[1];
    const int*   batch_idx  = (const int*)d_in[2];
    const float* W_rel0  = (const float*)d_in[3];
    const float* W_root0 = (const float*)d_in[4];
    const float* b0      = (const float*)d_in[5];
    const float* W_rel1  = (const float*)d_in[6];
    const float* W_root1 = (const float*)d_in[7];
    const float* b1      = (const float*)d_in[8];
    const float* W_rel2  = (const float*)d_in[9];
    const float* W_root2 = (const float*)d_in[10];
    const float* b2      = (const float*)d_in[11];
    const float* W_edge  = (const float*)d_in[12];
    const float* b_edge  = (const float*)d_in[13];

    const int* src = edge_index;
    const int* dst = edge_index + N_EDGES;

    char* ws = (char*)d_ws;
    size_t off = 0;
    auto alloc = [&](size_t bytes) -> char* {
        off = (off + 255) & ~(size_t)255;
        char* p = ws + off;
        off += bytes;
        return p;
    };
    unsigned short* xA    = (unsigned short*)alloc((size_t)N_NODES * HID * 2);  // x2
    unsigned short* xB    = (unsigned short*)alloc((size_t)N_NODES * HID * 2);  // x1 / x3
    unsigned short* Yrel  = (unsigned short*)alloc((size_t)N_NODES * HID * 2);
    unsigned short* Yroot = (unsigned short*)alloc((size_t)N_NODES * HID * 2);
    unsigned short* Wt0   = (unsigned short*)alloc(512 * 512 * 2);
    unsigned short* Wt1   = (unsigned short*)alloc(512 * 256 * 2);
    unsigned short* Wt2   = (unsigned short*)alloc(512 * 256 * 2);
    unsigned short* We2T  = (unsigned short*)alloc(32 * 256 * 2);
    float* P     = (float*)alloc((size_t)N_NODES * 32 * 4);
    int* counts  = (int*)alloc((size_t)N_NODES * 4);
    int* offsets = (int*)alloc((size_t)(N_NODES + 1) * 4);
    int* cur     = (int*)alloc((size_t)N_NODES * 4);
    int* csr     = (int*)alloc((size_t)N_EDGES * 4);
    int* bsum    = (int*)alloc(512 * 4);
    float* sums  = (float*)alloc(N_GRAPHS * HID * 4);

    const int nscan = (N_NODES + 255) / 256; // 391

    hipMemsetAsync(counts, 0, (size_t)N_NODES * 4, stream);
    hipMemsetAsync(sums, 0, N_GRAPHS * HID * 4, stream);

    // weight prep (one launch for all three layers)
    k_makeWtAll<<<dim3(8, 8, 3), 256, 0, stream>>>(W_rel0, W_root0, W_rel1, W_root1,
                                                   W_rel2, W_root2, Wt0, Wt1, Wt2);
    k_makeWe2T<<<32, 256, 0, stream>>>(W_edge, We2T);

    // CSR build
    k_hist<<<(N_EDGES + 255) / 256, 256, 0, stream>>>(dst, counts);
    k_scanA<<<nscan, 256, 0, stream>>>(counts, bsum);
    k_scanB<<<1, 256, 0, stream>>>(bsum, nscan);
    k_scanC<<<nscan, 256, 0, stream>>>(counts, bsum, offsets, cur);
    k_fill<<<(N_EDGES + 255) / 256, 256, 0, stream>>>(src, dst, cur, csr);

    const int gemmGrid = ((N_NODES + 127) / 128) * 4; // 3128, %8==0
    const int combGrid = (N_NODES + 7) / 8;           // 12500
    // layer 0 (fp32 A via async DMA staging, BK=32, cvt_pk on read)
    k_gemm0<<<gemmGrid, 256, 0, stream>>>(node_feats, Wt0, Yrel, Yroot, N_NODES);
    k_combine<<<combGrid, 256, 0, stream>>>(Yrel, Yroot, offsets, csr, b0, xB);
    // layer 1
    k_gemm<<<gemmGrid, 256, 0, stream>>>(xB, Wt1, Yrel, Yroot, N_NODES, 256);
    k_combine<<<combGrid, 256, 0, stream>>>(Yrel, Yroot, offsets, csr, b1, xA);
    // layer 2
    k_gemm<<<gemmGrid, 256, 0, stream>>>(xA, Wt2, Yrel, Yroot, N_NODES, 256);
    k_combine<<<combGrid, 256, 0, stream>>>(Yrel, Yroot, offsets, csr, b2, xB);

    // edge head -> d_out[0 : 8M)
    float* out_logits = (float*)d_out;
    k_proj<<<(N_NODES / 16 + 3) / 4, 256, 0, stream>>>(xB, We2T, P);
    k_edge_add<<<(N_EDGES + 255) / 256, 256, 0, stream>>>(P, src, dst, b_edge, out_logits);

    // mean pool -> d_out[8M : 8M+16384)
    float* out_embed = (float*)d_out + (size_t)N_EDGES * NREL;
    k_pool_sum<<<(N_NODES + 127) / 128, 256, 0, stream>>>(xB, batch_idx, sums);
    k_pool_final<<<N_GRAPHS, 256, 0, stream>>>(sums, batch_idx, out_embed);
}

// Round 14
// 497.223 us; speedup vs baseline: 1.0456x; 1.0456x over previous
//
#include <hip/hip_runtime.h>

#define N_NODES 100000
#define N_EDGES 500000
#define N_GRAPHS 64
#define IN_DIM 512
#define HID 256
#define NREL 16

using short8 = __attribute__((ext_vector_type(8))) short;
using f32x4  = __attribute__((ext_vector_type(4))) float;

__device__ __forceinline__ unsigned short f2bf(float f) {
    union { float f; unsigned u; } v; v.f = f;
    unsigned u = v.u;
    unsigned r = u + 0x7FFF + ((u >> 16) & 1);
    return (unsigned short)(r >> 16);
}
__device__ __forceinline__ float bf2f(unsigned short h) {
    union { unsigned u; float f; } v; v.u = ((unsigned)h) << 16;
    return v.f;
}
// packed fp32->bf16 RNE (native, gfx950)
__device__ __forceinline__ unsigned cvtpk(float lo, float hi) {
    unsigned r;
    asm("v_cvt_pk_bf16_f32 %0, %1, %2" : "=v"(r) : "v"(lo), "v"(hi));
    return r;
}

__device__ __forceinline__ void gload_lds16(const unsigned short* g, unsigned short* l) {
    __builtin_amdgcn_global_load_lds(
        (const __attribute__((address_space(1))) void*)(g),
        (__attribute__((address_space(3))) void*)(l), 16, 0, 0);
}
__device__ __forceinline__ void gload_lds16f(const float* g, float* l) {
    __builtin_amdgcn_global_load_lds(
        (const __attribute__((address_space(1))) void*)(g),
        (__attribute__((address_space(3))) void*)(l), 16, 0, 0);
}

// ---------------- weight prep (fused): Wt[n][k] = bf16(n<256 ? Wrel[k][n] : Wroot[k][n-256])
// grid = dim3(8, 8, 3); z selects layer; layers 1,2 use only blockIdx.x < 4 (K=256).
__global__ void k_makeWtAll(const float* __restrict__ Wrel0, const float* __restrict__ Wroot0,
                            const float* __restrict__ Wrel1, const float* __restrict__ Wroot1,
                            const float* __restrict__ Wrel2, const float* __restrict__ Wroot2,
                            unsigned short* __restrict__ Wt0, unsigned short* __restrict__ Wt1,
                            unsigned short* __restrict__ Wt2) {
    __shared__ float t[64][65];
    int z = blockIdx.z;
    int K = (z == 0) ? 512 : 256;
    if (blockIdx.x * 64 >= K) return;
    const float* Wrel  = (z == 0) ? Wrel0  : (z == 1) ? Wrel1  : Wrel2;
    const float* Wroot = (z == 0) ? Wroot0 : (z == 1) ? Wroot1 : Wroot2;
    unsigned short* Wt = (z == 0) ? Wt0    : (z == 1) ? Wt1    : Wt2;
    int tid = threadIdx.x;
    int tk = blockIdx.x * 64, tn = blockIdx.y * 64;
    const float* Wsrc = (tn < 256) ? Wrel : Wroot;
    int col0 = tn & 255;
    #pragma unroll
    for (int r = 0; r < 16; ++r) {
        int kl = r * 4 + (tid >> 6);
        int nl = tid & 63;
        t[kl][nl] = Wsrc[(size_t)(tk + kl) * 256 + col0 + nl];
    }
    __syncthreads();
    #pragma unroll
    for (int r = 0; r < 16; ++r) {
        int nl = r * 4 + (tid >> 6);
        int kl = tid & 63;
        Wt[(size_t)(tn + nl) * K + tk + kl] = f2bf(t[kl][nl]);
    }
}

// We2T[r][k], r<32, k<256
__global__ void k_makeWe2T(const float* __restrict__ We, unsigned short* __restrict__ We2T) {
    int idx = blockIdx.x * 256 + threadIdx.x;
    if (idx >= 32 * 256) return;
    int r = idx >> 8, k = idx & 255;
    float v = (r < 16) ? We[k * NREL + r] : We[(256 + k) * NREL + (r - 16)];
    We2T[idx] = f2bf(v);
}

// ---------------- CSR build ----------------
__global__ void k_hist(const int* __restrict__ dstArr, int* __restrict__ counts) {
    int i = blockIdx.x * 256 + threadIdx.x;
    if (i < N_EDGES) atomicAdd(&counts[dstArr[i]], 1);
}

__global__ void k_scanA(const int* __restrict__ counts, int* __restrict__ bsum) {
    __shared__ int ws[4];
    int i = blockIdx.x * 256 + threadIdx.x;
    int v = (i < N_NODES) ? counts[i] : 0;
    for (int o = 32; o; o >>= 1) v += __shfl_down(v, o, 64);
    if ((threadIdx.x & 63) == 0) ws[threadIdx.x >> 6] = v;
    __syncthreads();
    if (threadIdx.x == 0) bsum[blockIdx.x] = ws[0] + ws[1] + ws[2] + ws[3];
}

__global__ void k_scanB(int* __restrict__ bsum, int nb) {
    __shared__ int buf[512];
    int t = threadIdx.x;
    for (int i = t; i < nb; i += 256) buf[i] = bsum[i];
    __syncthreads();
    if (t == 0) { int s = 0; for (int i = 0; i < nb; ++i) { int x = buf[i]; buf[i] = s; s += x; } }
    __syncthreads();
    for (int i = t; i < nb; i += 256) bsum[i] = buf[i];
}

__global__ void k_scanC(const int* __restrict__ counts, const int* __restrict__ bsum,
                        int* __restrict__ offsets, int* __restrict__ cur) {
    __shared__ int ws[4];
    int i = blockIdx.x * 256 + threadIdx.x;
    int lane = threadIdx.x & 63, wid = threadIdx.x >> 6;
    int v = (i < N_NODES) ? counts[i] : 0;
    int x = v;
    for (int o = 1; o < 64; o <<= 1) { int u = __shfl_up(x, o, 64); if (lane >= o) x += u; }
    if (lane == 63) ws[wid] = x;
    __syncthreads();
    if (threadIdx.x == 0) { int s = 0; for (int t = 0; t < 4; ++t) { int tt = ws[t]; ws[t] = s; s += tt; } }
    __syncthreads();
    x += ws[wid];
    x += bsum[blockIdx.x];
    if (i < N_NODES) { offsets[i + 1] = x; cur[i] = x - v; }
    if (i == 0) offsets[0] = 0;
}

__global__ void k_fill(const int* __restrict__ srcArr, const int* __restrict__ dstArr,
                       int* __restrict__ cur, int* __restrict__ csr) {
    int i = blockIdx.x * 256 + threadIdx.x;
    if (i < N_EDGES) {
        int p = atomicAdd(&cur[dstArr[i]], 1);
        csr[p] = srcArr[i];
    }
}

// ---------------- GEMM (bf16 A): [Yrel|Yroot][M x 256] = A[M x K] @ Bt[512 x K]^T ----------
__global__ __launch_bounds__(256) void k_gemm(const unsigned short* __restrict__ A,
                                              const unsigned short* __restrict__ Bt,
                                              unsigned short* __restrict__ Yrel,
                                              unsigned short* __restrict__ Yroot,
                                              int M, int K) {
    __shared__ unsigned short lds[2 * 128 * 64];
    const int tid  = threadIdx.x;
    const int lane = tid & 63;
    const int w    = tid >> 6;
    const int wm   = w >> 1, wn = w & 1;

    int nwg  = gridDim.x;
    int orig = blockIdx.x;
    int q    = nwg >> 3;
    int id   = (orig & 7) * q + (orig >> 3);
    int bm0  = (id >> 2) * 128;
    int bn0  = (id & 3) * 128;

    f32x4 acc[4][4] = {};

    const int nkt = K >> 6;
    for (int kt = 0; kt < nkt; ++kt) {
        int k0 = kt << 6;
        #pragma unroll
        for (int it = 0; it < 4; ++it) {
            int c = (it << 8) + tid;
            int row = c >> 3, kcp = c & 7;
            int kcl = kcp ^ (row & 7);
            int gr = bm0 + row; gr = (gr < M) ? gr : (M - 1);
            gload_lds16(A + (size_t)gr * K + k0 + kcl * 8,
                        &lds[(size_t)((it << 8) + (w << 6)) * 8]);
        }
        #pragma unroll
        for (int it = 0; it < 4; ++it) {
            int c = (it << 8) + tid;
            int row = c >> 3, kcp = c & 7;
            int kcl = kcp ^ (row & 7);
            gload_lds16(Bt + (size_t)(bn0 + row) * K + k0 + kcl * 8,
                        &lds[128 * 64 + (size_t)((it << 8) + (w << 6)) * 8]);
        }
        __syncthreads();
        #pragma unroll
        for (int kk = 0; kk < 2; ++kk) {
            short8 af[4], bfr[4];
            #pragma unroll
            for (int m = 0; m < 4; ++m) {
                int row = wm * 64 + m * 16 + (lane & 15);
                int g = ((kk << 2) + (lane >> 4)) ^ (row & 7);
                af[m] = *(const short8*)&lds[row * 64 + g * 8];
            }
            #pragma unroll
            for (int n = 0; n < 4; ++n) {
                int row = wn * 64 + n * 16 + (lane & 15);
                int g = ((kk << 2) + (lane >> 4)) ^ (row & 7);
                bfr[n] = *(const short8*)&lds[128 * 64 + row * 64 + g * 8];
            }
            #pragma unroll
            for (int m = 0; m < 4; ++m)
                #pragma unroll
                for (int n = 0; n < 4; ++n)
                    acc[m][n] = __builtin_amdgcn_mfma_f32_16x16x32_bf16(af[m], bfr[n], acc[m][n], 0, 0, 0);
        }
        __syncthreads();
    }
    unsigned short* Cout = (bn0 < 256) ? Yrel : Yroot;
    int cb = bn0 & 255;
    #pragma unroll
    for (int m = 0; m < 4; ++m) {
        int row0 = bm0 + wm * 64 + m * 16 + ((lane >> 4) << 2);
        #pragma unroll
        for (int n = 0; n < 4; ++n) {
            int col = cb + wn * 64 + n * 16 + (lane & 15);
            #pragma unroll
            for (int i = 0; i < 4; ++i) {
                int r = row0 + i;
                if (r < M) Cout[(size_t)r * 256 + col] = f2bf(acc[m][n][i]);
            }
        }
    }
}

// ---------------- GEMM L0 (fp32 A via async global_load_lds, cvt_pk on fragment read) -------
// BK=64 verified template (R9): 48KB LDS, 0 bank conflicts, 138 us.
__global__ __launch_bounds__(256) void k_gemm0(const float* __restrict__ A,
                                               const unsigned short* __restrict__ Bt,
                                               unsigned short* __restrict__ Yrel,
                                               unsigned short* __restrict__ Yroot,
                                               int M) {
    constexpr int K = 512;
    __shared__ float ldsA[128 * 64];            // 32 KB
    __shared__ unsigned short ldsB[128 * 64];   // 16 KB
    const int tid  = threadIdx.x;
    const int lane = tid & 63;
    const int w    = tid >> 6;
    const int wm   = w >> 1, wn = w & 1;

    int nwg  = gridDim.x;
    int orig = blockIdx.x;
    int q    = nwg >> 3;
    int id   = (orig & 7) * q + (orig >> 3);
    int bm0  = (id >> 2) * 128;
    int bn0  = (id & 3) * 128;

    f32x4 acc[4][4] = {};

    const int nkt = K >> 6;
    for (int kt = 0; kt < nkt; ++kt) {
        int k0 = kt << 6;
        // stage A fp32 tile: 2048 granules of 16B, linear LDS dest, swizzled global source
        #pragma unroll
        for (int it = 0; it < 8; ++it) {
            int gi = (it << 8) + tid;
            int row = gi >> 4, gp = gi & 15;
            int gs = gp ^ (row & 15);
            int gr = bm0 + row; gr = (gr < M) ? gr : (M - 1);
            gload_lds16f(A + (size_t)gr * K + k0 + gs * 4,
                         &ldsA[(size_t)((it << 8) + (w << 6)) * 4]);
        }
        // stage B bf16 tile
        #pragma unroll
        for (int it = 0; it < 4; ++it) {
            int c = (it << 8) + tid;
            int row = c >> 3, kcp = c & 7;
            int kcl = kcp ^ (row & 7);
            gload_lds16(Bt + (size_t)(bn0 + row) * K + k0 + kcl * 8,
                        &ldsB[(size_t)((it << 8) + (w << 6)) * 8]);
        }
        __syncthreads();
        #pragma unroll
        for (int kk = 0; kk < 2; ++kk) {
            short8 af[4], bfr[4];
            #pragma unroll
            for (int m = 0; m < 4; ++m) {
                int row = wm * 64 + m * 16 + (lane & 15);
                int c = (kk << 2) + (lane >> 4);
                int g0 = (2 * c) ^ (row & 15);
                int g1 = (2 * c + 1) ^ (row & 15);
                f32x4 fa = *(const f32x4*)&ldsA[row * 64 + g0 * 4];
                f32x4 fb = *(const f32x4*)&ldsA[row * 64 + g1 * 4];
                union { short8 s8; unsigned u[4]; } vv;
                vv.u[0] = cvtpk(fa[0], fa[1]);
                vv.u[1] = cvtpk(fa[2], fa[3]);
                vv.u[2] = cvtpk(fb[0], fb[1]);
                vv.u[3] = cvtpk(fb[2], fb[3]);
                af[m] = vv.s8;
            }
            #pragma unroll
            for (int n = 0; n < 4; ++n) {
                int row = wn * 64 + n * 16 + (lane & 15);
                int g = ((kk << 2) + (lane >> 4)) ^ (row & 7);
                bfr[n] = *(const short8*)&ldsB[row * 64 + g * 8];
            }
            #pragma unroll
            for (int m = 0; m < 4; ++m)
                #pragma unroll
                for (int n = 0; n < 4; ++n)
                    acc[m][n] = __builtin_amdgcn_mfma_f32_16x16x32_bf16(af[m], bfr[n], acc[m][n], 0, 0, 0);
        }
        __syncthreads();
    }
    unsigned short* Cout = (bn0 < 256) ? Yrel : Yroot;
    int cb = bn0 & 255;
    #pragma unroll
    for (int m = 0; m < 4; ++m) {
        int row0 = bm0 + wm * 64 + m * 16 + ((lane >> 4) << 2);
        #pragma unroll
        for (int n = 0; n < 4; ++n) {
            int col = cb + wn * 64 + n * 16 + (lane & 15);
            #pragma unroll
            for (int i = 0; i < 4; ++i) {
                int r = row0 + i;
                if (r < M) Cout[(size_t)r * 256 + col] = f2bf(acc[m][n][i]);
            }
        }
    }
}

// ---------------- fused aggregate + root + bias + ReLU -> bf16 (2 nodes/wave, short8) -------
__device__ __forceinline__ void acc8(float4& lo, float4& hi, short8 v) {
    lo.x += bf2f((unsigned short)v[0]); lo.y += bf2f((unsigned short)v[1]);
    lo.z += bf2f((unsigned short)v[2]); lo.w += bf2f((unsigned short)v[3]);
    hi.x += bf2f((unsigned short)v[4]); hi.y += bf2f((unsigned short)v[5]);
    hi.z += bf2f((unsigned short)v[6]); hi.w += bf2f((unsigned short)v[7]);
}

__global__ void k_combine(const unsigned short* __restrict__ yrel,
                          const unsigned short* __restrict__ yroot,
                          const int* __restrict__ offs,
                          const int* __restrict__ csr, const float* __restrict__ bias,
                          unsigned short* __restrict__ xout) {
    int node = blockIdx.x * 8 + (threadIdx.x >> 5);
    if (node >= N_NODES) return;
    int l32 = threadIdx.x & 31;
    int d = l32 * 8;
    int j0 = offs[node], j1 = offs[node + 1];
    float4 a0l = {0,0,0,0}, a0h = {0,0,0,0};
    float4 a1l = {0,0,0,0}, a1h = {0,0,0,0};
    float4 a2l = {0,0,0,0}, a2h = {0,0,0,0};
    float4 a3l = {0,0,0,0}, a3h = {0,0,0,0};
    int j = j0;
    for (; j + 4 <= j1; j += 4) {
        int s0 = csr[j], s1 = csr[j + 1], s2 = csr[j + 2], s3 = csr[j + 3];
        short8 v0 = *(const short8*)(yrel + (size_t)s0 * 256 + d);
        short8 v1 = *(const short8*)(yrel + (size_t)s1 * 256 + d);
        short8 v2 = *(const short8*)(yrel + (size_t)s2 * 256 + d);
        short8 v3 = *(const short8*)(yrel + (size_t)s3 * 256 + d);
        acc8(a0l, a0h, v0); acc8(a1l, a1h, v1);
        acc8(a2l, a2h, v2); acc8(a3l, a3h, v3);
    }
    for (; j < j1; ++j) {
        int s = csr[j];
        acc8(a0l, a0h, *(const short8*)(yrel + (size_t)s * 256 + d));
    }
    a0l.x += a1l.x + a2l.x + a3l.x;  a0l.y += a1l.y + a2l.y + a3l.y;
    a0l.z += a1l.z + a2l.z + a3l.z;  a0l.w += a1l.w + a2l.w + a3l.w;
    a0h.x += a1h.x + a2h.x + a3h.x;  a0h.y += a1h.y + a2h.y + a3h.y;
    a0h.z += a1h.z + a2h.z + a3h.z;  a0h.w += a1h.w + a2h.w + a3h.w;
    short8 rr = *(const short8*)(yroot + (size_t)node * 256 + d);
    float4 bl = *(const float4*)(bias + d);
    float4 bh = *(const float4*)(bias + d + 4);
    short8 pk;
    pk[0] = (short)f2bf(fmaxf(a0l.x + bf2f((unsigned short)rr[0]) + bl.x, 0.f));
    pk[1] = (short)f2bf(fmaxf(a0l.y + bf2f((unsigned short)rr[1]) + bl.y, 0.f));
    pk[2] = (short)f2bf(fmaxf(a0l.z + bf2f((unsigned short)rr[2]) + bl.z, 0.f));
    pk[3] = (short)f2bf(fmaxf(a0l.w + bf2f((unsigned short)rr[3]) + bl.w, 0.f));
    pk[4] = (short)f2bf(fmaxf(a0h.x + bf2f((unsigned short)rr[4]) + bh.x, 0.f));
    pk[5] = (short)f2bf(fmaxf(a0h.y + bf2f((unsigned short)rr[5]) + bh.y, 0.f));
    pk[6] = (short)f2bf(fmaxf(a0h.z + bf2f((unsigned short)rr[6]) + bh.z, 0.f));
    pk[7] = (short)f2bf(fmaxf(a0h.w + bf2f((unsigned short)rr[7]) + bh.w, 0.f));
    *(short8*)(xout + (size_t)node * HID + d) = pk;
}

// ---------------- edge head, stage 1: P[N x 32] = x3 @ We2T^T (fp32 out) ----------------
__global__ void k_proj(const unsigned short* __restrict__ x,
                       const unsigned short* __restrict__ We2T,
                       float* __restrict__ P) {
    int lane = threadIdx.x & 63;
    int g = blockIdx.x * 4 + (threadIdx.x >> 6);
    if (g * 16 >= N_NODES) return;
    int n0 = g * 16;
    short8 bfr[2][8];
    #pragma unroll
    for (int cg = 0; cg < 2; ++cg)
        #pragma unroll
        for (int ks = 0; ks < 8; ++ks)
            bfr[cg][ks] = *(const short8*)&We2T[(size_t)(cg * 16 + (lane & 15)) * 256 + ks * 32 + ((lane >> 4) << 3)];
    f32x4 acc[2] = {};
    const size_t rb = (size_t)(n0 + (lane & 15)) * 256 + ((lane >> 4) << 3);
    #pragma unroll
    for (int ks = 0; ks < 8; ++ks) {
        short8 af = *(const short8*)&x[rb + ks * 32];
        acc[0] = __builtin_amdgcn_mfma_f32_16x16x32_bf16(af, bfr[0][ks], acc[0], 0, 0, 0);
        acc[1] = __builtin_amdgcn_mfma_f32_16x16x32_bf16(af, bfr[1][ks], acc[1], 0, 0, 0);
    }
    #pragma unroll
    for (int cg = 0; cg < 2; ++cg) {
        #pragma unroll
        for (int i = 0; i < 4; ++i) {
            int n = n0 + ((lane >> 4) << 2) + i;
            P[(size_t)n * 32 + cg * 16 + (lane & 15)] = acc[cg][i];
        }
    }
}

// ---------------- edge head, stage 2 ----------
__global__ void k_edge_add(const float* __restrict__ P,
                           const int* __restrict__ srcArr, const int* __restrict__ dstArr,
                           const float* __restrict__ b_edge, float* __restrict__ out) {
    int e = blockIdx.x * 256 + threadIdx.x;
    if (e >= N_EDGES) return;
    int s = srcArr[e], d = dstArr[e];
    const float4* ps = (const float4*)(P + (size_t)s * 32);
    const float4* pd = (const float4*)(P + (size_t)d * 32 + 16);
    const float4* bb = (const float4*)b_edge;
    float4* po = (float4*)(out + (size_t)e * 16);
    #pragma unroll
    for (int i = 0; i < 4; ++i) {
        float4 a = ps[i], b = pd[i], c = bb[i];
        float4 rr;
        rr.x = a.x + b.x + c.x; rr.y = a.y + b.y + c.y;
        rr.z = a.z + b.z + c.z; rr.w = a.w + b.w + c.w;
        po[i] = rr;
    }
}

// ---------------- mean pool ----------------
__global__ void k_pool_sum(const unsigned short* __restrict__ x, const int* __restrict__ batch,
                           float* __restrict__ sums) {
    const int CH = 32;
    int w = threadIdx.x >> 6, lane = threadIdx.x & 63;
    int n0 = blockIdx.x * (4 * CH) + w * CH;
    if (n0 >= N_NODES) return;
    int n1 = n0 + CH; if (n1 > N_NODES) n1 = N_NODES;
    int d = lane * 4;
    float a0 = 0.f, a1 = 0.f, a2 = 0.f, a3 = 0.f;
    int gcur = batch[n0];
    for (int n = n0; n < n1; ++n) {
        int g = batch[n];
        if (g != gcur) {
            float* p = &sums[gcur * HID + d];
            atomicAdd(p + 0, a0); atomicAdd(p + 1, a1);
            atomicAdd(p + 2, a2); atomicAdd(p + 3, a3);
            a0 = a1 = a2 = a3 = 0.f; gcur = g;
        }
        ushort4 v = *(const ushort4*)&x[(size_t)n * HID + d];
        a0 += bf2f(v.x); a1 += bf2f(v.y); a2 += bf2f(v.z); a3 += bf2f(v.w);
    }
    float* p = &sums[gcur * HID + d];
    atomicAdd(p + 0, a0); atomicAdd(p + 1, a1);
    atomicAdd(p + 2, a2); atomicAdd(p + 3, a3);
}

__device__ __forceinline__ int lowerBound(const int* a, int n, int key) {
    int lo = 0, hi = n;
    while (lo < hi) { int mid = (lo + hi) >> 1; if (a[mid] < key) lo = mid + 1; else hi = mid; }
    return lo;
}

__global__ void k_pool_final(const float* __restrict__ sums, const int* __restrict__ batch,
                             float* __restrict__ out) {
    int g = blockIdx.x, d = threadIdx.x;
    int lo = lowerBound(batch, N_NODES, g);
    int hi = lowerBound(batch, N_NODES, g + 1);
    float cnt = (float)(hi - lo);
    out[(size_t)g * HID + d] = sums[g * HID + d] / fmaxf(cnt, 1.0f);
}

// ---------------- launcher ----------------
extern "C" void kernel_launch(void* const* d_in, const int* in_sizes, int n_in,
                              void* d_out, int out_size, void* d_ws, size_t ws_size,
                              hipStream_t stream) {
    const float* node_feats = (const float*)d_in[0];
    const int*   edge_index = (const int*)d_in[1];
    const int*   batch_idx  = (const int*)d_in[2];
    const float* W_rel0  = (const float*)d_in[3];
    const float* W_root0 = (const float*)d_in[4];
    const float* b0      = (const float*)d_in[5];
    const float* W_rel1  = (const float*)d_in[6];
    const float* W_root1 = (const float*)d_in[7];
    const float* b1      = (const float*)d_in[8];
    const float* W_rel2  = (const float*)d_in[9];
    const float* W_root2 = (const float*)d_in[10];
    const float* b2      = (const float*)d_in[11];
    const float* W_edge  = (const float*)d_in[12];
    const float* b_edge  = (const float*)d_in[13];

    const int* src = edge_index;
    const int* dst = edge_index + N_EDGES;

    char* ws = (char*)d_ws;
    size_t off = 0;
    auto alloc = [&](size_t bytes) -> char* {
        off = (off + 255) & ~(size_t)255;
        char* p = ws + off;
        off += bytes;
        return p;
    };
    unsigned short* xA    = (unsigned short*)alloc((size_t)N_NODES * HID * 2);  // x2
    unsigned short* xB    = (unsigned short*)alloc((size_t)N_NODES * HID * 2);  // x1 / x3
    unsigned short* Yrel  = (unsigned short*)alloc((size_t)N_NODES * HID * 2);
    unsigned short* Yroot = (unsigned short*)alloc((size_t)N_NODES * HID * 2);
    unsigned short* Wt0   = (unsigned short*)alloc(512 * 512 * 2);
    unsigned short* Wt1   = (unsigned short*)alloc(512 * 256 * 2);
    unsigned short* Wt2   = (unsigned short*)alloc(512 * 256 * 2);
    unsigned short* We2T  = (unsigned short*)alloc(32 * 256 * 2);
    float* P     = (float*)alloc((size_t)N_NODES * 32 * 4);
    int* counts  = (int*)alloc((size_t)N_NODES * 4);
    int* offsets = (int*)alloc((size_t)(N_NODES + 1) * 4);
    int* cur     = (int*)alloc((size_t)N_NODES * 4);
    int* csr     = (int*)alloc((size_t)N_EDGES * 4);
    int* bsum    = (int*)alloc(512 * 4);
    float* sums  = (float*)alloc(N_GRAPHS * HID * 4);

    const int nscan = (N_NODES + 255) / 256; // 391

    hipMemsetAsync(counts, 0, (size_t)N_NODES * 4, stream);
    hipMemsetAsync(sums, 0, N_GRAPHS * HID * 4, stream);

    // weight prep (one launch for all three layers)
    k_makeWtAll<<<dim3(8, 8, 3), 256, 0, stream>>>(W_rel0, W_root0, W_rel1, W_root1,
                                                   W_rel2, W_root2, Wt0, Wt1, Wt2);
    k_makeWe2T<<<32, 256, 0, stream>>>(W_edge, We2T);

    // CSR build
    k_hist<<<(N_EDGES + 255) / 256, 256, 0, stream>>>(dst, counts);
    k_scanA<<<nscan, 256, 0, stream>>>(counts, bsum);
    k_scanB<<<1, 256, 0, stream>>>(bsum, nscan);
    k_scanC<<<nscan, 256, 0, stream>>>(counts, bsum, offsets, cur);
    k_fill<<<(N_EDGES + 255) / 256, 256, 0, stream>>>(src, dst, cur, csr);

    const int gemmGrid = ((N_NODES + 127) / 128) * 4; // 3128, %8==0
    const int combGrid = (N_NODES + 7) / 8;           // 12500
    // layer 0 (fp32 A via async DMA staging, BK=64, cvt_pk on read)
    k_gemm0<<<gemmGrid, 256, 0, stream>>>(node_feats, Wt0, Yrel, Yroot, N_NODES);
    k_combine<<<combGrid, 256, 0, stream>>>(Yrel, Yroot, offsets, csr, b0, xB);
    // layer 1
    k_gemm<<<gemmGrid, 256, 0, stream>>>(xB, Wt1, Yrel, Yroot, N_NODES, 256);
    k_combine<<<combGrid, 256, 0, stream>>>(Yrel, Yroot, offsets, csr, b1, xA);
    // layer 2
    k_gemm<<<gemmGrid, 256, 0, stream>>>(xA, Wt2, Yrel, Yroot, N_NODES, 256);
    k_combine<<<combGrid, 256, 0, stream>>>(Yrel, Yroot, offsets, csr, b2, xB);

    // edge head -> d_out[0 : 8M)
    float* out_logits = (float*)d_out;
    k_proj<<<(N_NODES / 16 + 3) / 4, 256, 0, stream>>>(xB, We2T, P);
    k_edge_add<<<(N_EDGES + 255) / 256, 256, 0, stream>>>(P, src, dst, b_edge, out_logits);

    // mean pool -> d_out[8M : 8M+16384)
    float* out_embed = (float*)d_out + (size_t)N_EDGES * NREL;
    k_pool_sum<<<(N_NODES + 127) / 128, 256, 0, stream>>>(xB, batch_idx, sums);
    k_pool_final<<<N_GRAPHS, 256, 0, stream>>>(sums, batch_idx, out_embed);
}

// Round 15
// 477.814 us; speedup vs baseline: 1.0880x; 1.0406x over previous
//
#include <hip/hip_runtime.h>

#define N_NODES 100000
#define N_EDGES 500000
#define N_GRAPHS 64
#define IN_DIM 512
#define HID 256
#define NREL 16

using short8 = __attribute__((ext_vector_type(8))) short;
using f32x4  = __attribute__((ext_vector_type(4))) float;

__device__ __forceinline__ unsigned short f2bf(float f) {
    union { float f; unsigned u; } v; v.f = f;
    unsigned u = v.u;
    unsigned r = u + 0x7FFF + ((u >> 16) & 1);
    return (unsigned short)(r >> 16);
}
__device__ __forceinline__ float bf2f(unsigned short h) {
    union { unsigned u; float f; } v; v.u = ((unsigned)h) << 16;
    return v.f;
}
// packed fp32->bf16 RNE (native, gfx950)
__device__ __forceinline__ unsigned cvtpk(float lo, float hi) {
    unsigned r;
    asm("v_cvt_pk_bf16_f32 %0, %1, %2" : "=v"(r) : "v"(lo), "v"(hi));
    return r;
}

__device__ __forceinline__ void gload_lds16(const unsigned short* g, unsigned short* l) {
    __builtin_amdgcn_global_load_lds(
        (const __attribute__((address_space(1))) void*)(g),
        (__attribute__((address_space(3))) void*)(l), 16, 0, 0);
}
__device__ __forceinline__ void gload_lds16f(const float* g, float* l) {
    __builtin_amdgcn_global_load_lds(
        (const __attribute__((address_space(1))) void*)(g),
        (__attribute__((address_space(3))) void*)(l), 16, 0, 0);
}

// ---------------- fused prep: weights (3 layers + edge head) + buffer zeroing --------------
// grid = dim3(8, 8, 4); z in {0,1,2}: Wt layer z (layers 1,2 use blockIdx.x<4);
// z==3: We2T + zero counts/sums (grid-stride).
__global__ void k_makeWtAll(const float* __restrict__ Wrel0, const float* __restrict__ Wroot0,
                            const float* __restrict__ Wrel1, const float* __restrict__ Wroot1,
                            const float* __restrict__ Wrel2, const float* __restrict__ Wroot2,
                            const float* __restrict__ We,
                            unsigned short* __restrict__ Wt0, unsigned short* __restrict__ Wt1,
                            unsigned short* __restrict__ Wt2, unsigned short* __restrict__ We2T,
                            int* __restrict__ counts, float* __restrict__ sums) {
    int z = blockIdx.z;
    int tid = threadIdx.x;
    if (z == 3) {
        int bid = blockIdx.y * 8 + blockIdx.x;      // 0..63
        int idx = bid * 256 + tid;                  // 0..16383
        if (idx < 32 * 256) {
            int r = idx >> 8, k = idx & 255;
            float v = (r < 16) ? We[k * NREL + r] : We[(256 + k) * NREL + (r - 16)];
            We2T[idx] = f2bf(v);
        }
        for (int i = idx; i < N_NODES; i += 64 * 256) counts[i] = 0;
        if (idx < N_GRAPHS * HID) sums[idx] = 0.f;
        return;
    }
    __shared__ float t[64][65];
    int K = (z == 0) ? 512 : 256;
    if (blockIdx.x * 64 >= K) return;
    const float* Wrel  = (z == 0) ? Wrel0  : (z == 1) ? Wrel1  : Wrel2;
    const float* Wroot = (z == 0) ? Wroot0 : (z == 1) ? Wroot1 : Wroot2;
    unsigned short* Wt = (z == 0) ? Wt0    : (z == 1) ? Wt1    : Wt2;
    int tk = blockIdx.x * 64, tn = blockIdx.y * 64;
    const float* Wsrc = (tn < 256) ? Wrel : Wroot;
    int col0 = tn & 255;
    #pragma unroll
    for (int r = 0; r < 16; ++r) {
        int kl = r * 4 + (tid >> 6);
        int nl = tid & 63;
        t[kl][nl] = Wsrc[(size_t)(tk + kl) * 256 + col0 + nl];
    }
    __syncthreads();
    #pragma unroll
    for (int r = 0; r < 16; ++r) {
        int nl = r * 4 + (tid >> 6);
        int kl = tid & 63;
        Wt[(size_t)(tn + nl) * K + tk + kl] = f2bf(t[kl][nl]);
    }
}

// ---------------- CSR build ----------------
__global__ void k_hist(const int* __restrict__ dstArr, int* __restrict__ counts) {
    int i = blockIdx.x * 256 + threadIdx.x;
    if (i < N_EDGES) atomicAdd(&counts[dstArr[i]], 1);
}

__global__ void k_scanA(const int* __restrict__ counts, int* __restrict__ bsum) {
    __shared__ int ws[4];
    int i = blockIdx.x * 256 + threadIdx.x;
    int v = (i < N_NODES) ? counts[i] : 0;
    for (int o = 32; o; o >>= 1) v += __shfl_down(v, o, 64);
    if ((threadIdx.x & 63) == 0) ws[threadIdx.x >> 6] = v;
    __syncthreads();
    if (threadIdx.x == 0) bsum[blockIdx.x] = ws[0] + ws[1] + ws[2] + ws[3];
}

__global__ void k_scanB(int* __restrict__ bsum, int nb) {
    __shared__ int buf[512];
    int t = threadIdx.x;
    for (int i = t; i < nb; i += 256) buf[i] = bsum[i];
    __syncthreads();
    if (t == 0) { int s = 0; for (int i = 0; i < nb; ++i) { int x = buf[i]; buf[i] = s; s += x; } }
    __syncthreads();
    for (int i = t; i < nb; i += 256) bsum[i] = buf[i];
}

__global__ void k_scanC(const int* __restrict__ counts, const int* __restrict__ bsum,
                        int* __restrict__ offsets, int* __restrict__ cur) {
    __shared__ int ws[4];
    int i = blockIdx.x * 256 + threadIdx.x;
    int lane = threadIdx.x & 63, wid = threadIdx.x >> 6;
    int v = (i < N_NODES) ? counts[i] : 0;
    int x = v;
    for (int o = 1; o < 64; o <<= 1) { int u = __shfl_up(x, o, 64); if (lane >= o) x += u; }
    if (lane == 63) ws[wid] = x;
    __syncthreads();
    if (threadIdx.x == 0) { int s = 0; for (int t = 0; t < 4; ++t) { int tt = ws[t]; ws[t] = s; s += tt; } }
    __syncthreads();
    x += ws[wid];
    x += bsum[blockIdx.x];
    if (i < N_NODES) { offsets[i + 1] = x; cur[i] = x - v; }
    if (i == 0) offsets[0] = 0;
}

__global__ void k_fill(const int* __restrict__ srcArr, const int* __restrict__ dstArr,
                       int* __restrict__ cur, int* __restrict__ csr) {
    int i = blockIdx.x * 256 + threadIdx.x;
    if (i < N_EDGES) {
        int p = atomicAdd(&cur[dstArr[i]], 1);
        csr[p] = srcArr[i];
    }
}

// ---------------- GEMM (bf16 A): [Yrel|Yroot][M x 256] = A[M x K] @ Bt[512 x K]^T ----------
__global__ __launch_bounds__(256) void k_gemm(const unsigned short* __restrict__ A,
                                              const unsigned short* __restrict__ Bt,
                                              unsigned short* __restrict__ Yrel,
                                              unsigned short* __restrict__ Yroot,
                                              int M, int K) {
    __shared__ unsigned short lds[2 * 128 * 64];
    const int tid  = threadIdx.x;
    const int lane = tid & 63;
    const int w    = tid >> 6;
    const int wm   = w >> 1, wn = w & 1;

    int nwg  = gridDim.x;
    int orig = blockIdx.x;
    int q    = nwg >> 3;
    int id   = (orig & 7) * q + (orig >> 3);
    int bm0  = (id >> 2) * 128;
    int bn0  = (id & 3) * 128;

    f32x4 acc[4][4] = {};

    const int nkt = K >> 6;
    for (int kt = 0; kt < nkt; ++kt) {
        int k0 = kt << 6;
        #pragma unroll
        for (int it = 0; it < 4; ++it) {
            int c = (it << 8) + tid;
            int row = c >> 3, kcp = c & 7;
            int kcl = kcp ^ (row & 7);
            int gr = bm0 + row; gr = (gr < M) ? gr : (M - 1);
            gload_lds16(A + (size_t)gr * K + k0 + kcl * 8,
                        &lds[(size_t)((it << 8) + (w << 6)) * 8]);
        }
        #pragma unroll
        for (int it = 0; it < 4; ++it) {
            int c = (it << 8) + tid;
            int row = c >> 3, kcp = c & 7;
            int kcl = kcp ^ (row & 7);
            gload_lds16(Bt + (size_t)(bn0 + row) * K + k0 + kcl * 8,
                        &lds[128 * 64 + (size_t)((it << 8) + (w << 6)) * 8]);
        }
        __syncthreads();
        #pragma unroll
        for (int kk = 0; kk < 2; ++kk) {
            short8 af[4], bfr[4];
            #pragma unroll
            for (int m = 0; m < 4; ++m) {
                int row = wm * 64 + m * 16 + (lane & 15);
                int g = ((kk << 2) + (lane >> 4)) ^ (row & 7);
                af[m] = *(const short8*)&lds[row * 64 + g * 8];
            }
            #pragma unroll
            for (int n = 0; n < 4; ++n) {
                int row = wn * 64 + n * 16 + (lane & 15);
                int g = ((kk << 2) + (lane >> 4)) ^ (row & 7);
                bfr[n] = *(const short8*)&lds[128 * 64 + row * 64 + g * 8];
            }
            #pragma unroll
            for (int m = 0; m < 4; ++m)
                #pragma unroll
                for (int n = 0; n < 4; ++n)
                    acc[m][n] = __builtin_amdgcn_mfma_f32_16x16x32_bf16(af[m], bfr[n], acc[m][n], 0, 0, 0);
        }
        __syncthreads();
    }
    unsigned short* Cout = (bn0 < 256) ? Yrel : Yroot;
    int cb = bn0 & 255;
    #pragma unroll
    for (int m = 0; m < 4; ++m) {
        int row0 = bm0 + wm * 64 + m * 16 + ((lane >> 4) << 2);
        #pragma unroll
        for (int n = 0; n < 4; ++n) {
            int col = cb + wn * 64 + n * 16 + (lane & 15);
            #pragma unroll
            for (int i = 0; i < 4; ++i) {
                int r = row0 + i;
                if (r < M) Cout[(size_t)r * 256 + col] = f2bf(acc[m][n][i]);
            }
        }
    }
}

// ---------------- GEMM L0 (fp32 A via async global_load_lds, cvt_pk on fragment read) -------
__global__ __launch_bounds__(256) void k_gemm0(const float* __restrict__ A,
                                               const unsigned short* __restrict__ Bt,
                                               unsigned short* __restrict__ Yrel,
                                               unsigned short* __restrict__ Yroot,
                                               int M) {
    constexpr int K = 512;
    __shared__ float ldsA[128 * 64];            // 32 KB
    __shared__ unsigned short ldsB[128 * 64];   // 16 KB
    const int tid  = threadIdx.x;
    const int lane = tid & 63;
    const int w    = tid >> 6;
    const int wm   = w >> 1, wn = w & 1;

    int nwg  = gridDim.x;
    int orig = blockIdx.x;
    int q    = nwg >> 3;
    int id   = (orig & 7) * q + (orig >> 3);
    int bm0  = (id >> 2) * 128;
    int bn0  = (id & 3) * 128;

    f32x4 acc[4][4] = {};

    const int nkt = K >> 6;
    for (int kt = 0; kt < nkt; ++kt) {
        int k0 = kt << 6;
        #pragma unroll
        for (int it = 0; it < 8; ++it) {
            int gi = (it << 8) + tid;
            int row = gi >> 4, gp = gi & 15;
            int gs = gp ^ (row & 15);
            int gr = bm0 + row; gr = (gr < M) ? gr : (M - 1);
            gload_lds16f(A + (size_t)gr * K + k0 + gs * 4,
                         &ldsA[(size_t)((it << 8) + (w << 6)) * 4]);
        }
        #pragma unroll
        for (int it = 0; it < 4; ++it) {
            int c = (it << 8) + tid;
            int row = c >> 3, kcp = c & 7;
            int kcl = kcp ^ (row & 7);
            gload_lds16(Bt + (size_t)(bn0 + row) * K + k0 + kcl * 8,
                        &ldsB[(size_t)((it << 8) + (w << 6)) * 8]);
        }
        __syncthreads();
        #pragma unroll
        for (int kk = 0; kk < 2; ++kk) {
            short8 af[4], bfr[4];
            #pragma unroll
            for (int m = 0; m < 4; ++m) {
                int row = wm * 64 + m * 16 + (lane & 15);
                int c = (kk << 2) + (lane >> 4);
                int g0 = (2 * c) ^ (row & 15);
                int g1 = (2 * c + 1) ^ (row & 15);
                f32x4 fa = *(const f32x4*)&ldsA[row * 64 + g0 * 4];
                f32x4 fb = *(const f32x4*)&ldsA[row * 64 + g1 * 4];
                union { short8 s8; unsigned u[4]; } vv;
                vv.u[0] = cvtpk(fa[0], fa[1]);
                vv.u[1] = cvtpk(fa[2], fa[3]);
                vv.u[2] = cvtpk(fb[0], fb[1]);
                vv.u[3] = cvtpk(fb[2], fb[3]);
                af[m] = vv.s8;
            }
            #pragma unroll
            for (int n = 0; n < 4; ++n) {
                int row = wn * 64 + n * 16 + (lane & 15);
                int g = ((kk << 2) + (lane >> 4)) ^ (row & 7);
                bfr[n] = *(const short8*)&ldsB[row * 64 + g * 8];
            }
            #pragma unroll
            for (int m = 0; m < 4; ++m)
                #pragma unroll
                for (int n = 0; n < 4; ++n)
                    acc[m][n] = __builtin_amdgcn_mfma_f32_16x16x32_bf16(af[m], bfr[n], acc[m][n], 0, 0, 0);
        }
        __syncthreads();
    }
    unsigned short* Cout = (bn0 < 256) ? Yrel : Yroot;
    int cb = bn0 & 255;
    #pragma unroll
    for (int m = 0; m < 4; ++m) {
        int row0 = bm0 + wm * 64 + m * 16 + ((lane >> 4) << 2);
        #pragma unroll
        for (int n = 0; n < 4; ++n) {
            int col = cb + wn * 64 + n * 16 + (lane & 15);
            #pragma unroll
            for (int i = 0; i < 4; ++i) {
                int r = row0 + i;
                if (r < M) Cout[(size_t)r * 256 + col] = f2bf(acc[m][n][i]);
            }
        }
    }
}

// ---------------- fused aggregate + root + bias + ReLU -> bf16 (2 nodes/wave, short8) -------
__device__ __forceinline__ void acc8(float4& lo, float4& hi, short8 v) {
    lo.x += bf2f((unsigned short)v[0]); lo.y += bf2f((unsigned short)v[1]);
    lo.z += bf2f((unsigned short)v[2]); lo.w += bf2f((unsigned short)v[3]);
    hi.x += bf2f((unsigned short)v[4]); hi.y += bf2f((unsigned short)v[5]);
    hi.z += bf2f((unsigned short)v[6]); hi.w += bf2f((unsigned short)v[7]);
}

__global__ void k_combine(const unsigned short* __restrict__ yrel,
                          const unsigned short* __restrict__ yroot,
                          const int* __restrict__ offs,
                          const int* __restrict__ csr, const float* __restrict__ bias,
                          unsigned short* __restrict__ xout) {
    int node = blockIdx.x * 8 + (threadIdx.x >> 5);
    if (node >= N_NODES) return;
    int l32 = threadIdx.x & 31;
    int d = l32 * 8;
    int j0 = offs[node], j1 = offs[node + 1];
    float4 a0l = {0,0,0,0}, a0h = {0,0,0,0};
    float4 a1l = {0,0,0,0}, a1h = {0,0,0,0};
    float4 a2l = {0,0,0,0}, a2h = {0,0,0,0};
    float4 a3l = {0,0,0,0}, a3h = {0,0,0,0};
    int j = j0;
    for (; j + 4 <= j1; j += 4) {
        int s0 = csr[j], s1 = csr[j + 1], s2 = csr[j + 2], s3 = csr[j + 3];
        short8 v0 = *(const short8*)(yrel + (size_t)s0 * 256 + d);
        short8 v1 = *(const short8*)(yrel + (size_t)s1 * 256 + d);
        short8 v2 = *(const short8*)(yrel + (size_t)s2 * 256 + d);
        short8 v3 = *(const short8*)(yrel + (size_t)s3 * 256 + d);
        acc8(a0l, a0h, v0); acc8(a1l, a1h, v1);
        acc8(a2l, a2h, v2); acc8(a3l, a3h, v3);
    }
    for (; j < j1; ++j) {
        int s = csr[j];
        acc8(a0l, a0h, *(const short8*)(yrel + (size_t)s * 256 + d));
    }
    a0l.x += a1l.x + a2l.x + a3l.x;  a0l.y += a1l.y + a2l.y + a3l.y;
    a0l.z += a1l.z + a2l.z + a3l.z;  a0l.w += a1l.w + a2l.w + a3l.w;
    a0h.x += a1h.x + a2h.x + a3h.x;  a0h.y += a1h.y + a2h.y + a3h.y;
    a0h.z += a1h.z + a2h.z + a3h.z;  a0h.w += a1h.w + a2h.w + a3h.w;
    short8 rr = *(const short8*)(yroot + (size_t)node * 256 + d);
    float4 bl = *(const float4*)(bias + d);
    float4 bh = *(const float4*)(bias + d + 4);
    short8 pk;
    pk[0] = (short)f2bf(fmaxf(a0l.x + bf2f((unsigned short)rr[0]) + bl.x, 0.f));
    pk[1] = (short)f2bf(fmaxf(a0l.y + bf2f((unsigned short)rr[1]) + bl.y, 0.f));
    pk[2] = (short)f2bf(fmaxf(a0l.z + bf2f((unsigned short)rr[2]) + bl.z, 0.f));
    pk[3] = (short)f2bf(fmaxf(a0l.w + bf2f((unsigned short)rr[3]) + bl.w, 0.f));
    pk[4] = (short)f2bf(fmaxf(a0h.x + bf2f((unsigned short)rr[4]) + bh.x, 0.f));
    pk[5] = (short)f2bf(fmaxf(a0h.y + bf2f((unsigned short)rr[5]) + bh.y, 0.f));
    pk[6] = (short)f2bf(fmaxf(a0h.z + bf2f((unsigned short)rr[6]) + bh.z, 0.f));
    pk[7] = (short)f2bf(fmaxf(a0h.w + bf2f((unsigned short)rr[7]) + bh.w, 0.f));
    *(short8*)(xout + (size_t)node * HID + d) = pk;
}

// ---------------- merged: edge proj (P = x3 @ We2T^T) + mean-pool partial sums --------------
// blocks [0, PROJ_BLKS): proj; blocks [PROJ_BLKS, PROJ_BLKS+POOL_BLKS): pool_sum.
#define PROJ_BLKS 1563
#define POOL_BLKS 782
__global__ void k_proj_pool(const unsigned short* __restrict__ x,
                            const unsigned short* __restrict__ We2T,
                            const int* __restrict__ batch,
                            float* __restrict__ P, float* __restrict__ sums) {
    if (blockIdx.x < PROJ_BLKS) {
        int lane = threadIdx.x & 63;
        int g = blockIdx.x * 4 + (threadIdx.x >> 6);
        if (g * 16 >= N_NODES) return;
        int n0 = g * 16;
        short8 bfr[2][8];
        #pragma unroll
        for (int cg = 0; cg < 2; ++cg)
            #pragma unroll
            for (int ks = 0; ks < 8; ++ks)
                bfr[cg][ks] = *(const short8*)&We2T[(size_t)(cg * 16 + (lane & 15)) * 256 + ks * 32 + ((lane >> 4) << 3)];
        f32x4 acc[2] = {};
        const size_t rb = (size_t)(n0 + (lane & 15)) * 256 + ((lane >> 4) << 3);
        #pragma unroll
        for (int ks = 0; ks < 8; ++ks) {
            short8 af = *(const short8*)&x[rb + ks * 32];
            acc[0] = __builtin_amdgcn_mfma_f32_16x16x32_bf16(af, bfr[0][ks], acc[0], 0, 0, 0);
            acc[1] = __builtin_amdgcn_mfma_f32_16x16x32_bf16(af, bfr[1][ks], acc[1], 0, 0, 0);
        }
        #pragma unroll
        for (int cg = 0; cg < 2; ++cg) {
            #pragma unroll
            for (int i = 0; i < 4; ++i) {
                int n = n0 + ((lane >> 4) << 2) + i;
                P[(size_t)n * 32 + cg * 16 + (lane & 15)] = acc[cg][i];
            }
        }
    } else {
        const int CH = 32;
        int bid = blockIdx.x - PROJ_BLKS;
        int w = threadIdx.x >> 6, lane = threadIdx.x & 63;
        int n0 = bid * (4 * CH) + w * CH;
        if (n0 >= N_NODES) return;
        int n1 = n0 + CH; if (n1 > N_NODES) n1 = N_NODES;
        int d = lane * 4;
        float a0 = 0.f, a1 = 0.f, a2 = 0.f, a3 = 0.f;
        int gcur = batch[n0];
        for (int n = n0; n < n1; ++n) {
            int g = batch[n];
            if (g != gcur) {
                float* p = &sums[gcur * HID + d];
                atomicAdd(p + 0, a0); atomicAdd(p + 1, a1);
                atomicAdd(p + 2, a2); atomicAdd(p + 3, a3);
                a0 = a1 = a2 = a3 = 0.f; gcur = g;
            }
            ushort4 v = *(const ushort4*)&x[(size_t)n * HID + d];
            a0 += bf2f(v.x); a1 += bf2f(v.y); a2 += bf2f(v.z); a3 += bf2f(v.w);
        }
        float* p = &sums[gcur * HID + d];
        atomicAdd(p + 0, a0); atomicAdd(p + 1, a1);
        atomicAdd(p + 2, a2); atomicAdd(p + 3, a3);
    }
}

__device__ __forceinline__ int lowerBound(const int* a, int n, int key) {
    int lo = 0, hi = n;
    while (lo < hi) { int mid = (lo + hi) >> 1; if (a[mid] < key) lo = mid + 1; else hi = mid; }
    return lo;
}

// ---------------- edge head add + (blocks 0..63) mean-pool finalize -------------------------
__global__ void k_edge_add(const float* __restrict__ P,
                           const int* __restrict__ srcArr, const int* __restrict__ dstArr,
                           const float* __restrict__ b_edge, float* __restrict__ out,
                           const float* __restrict__ sums, const int* __restrict__ batch,
                           float* __restrict__ out_embed) {
    int e = blockIdx.x * 256 + threadIdx.x;
    if (e < N_EDGES) {
        int s = srcArr[e], d = dstArr[e];
        const float4* ps = (const float4*)(P + (size_t)s * 32);
        const float4* pd = (const float4*)(P + (size_t)d * 32 + 16);
        const float4* bb = (const float4*)b_edge;
        float4* po = (float4*)(out + (size_t)e * 16);
        #pragma unroll
        for (int i = 0; i < 4; ++i) {
            float4 a = ps[i], b = pd[i], c = bb[i];
            float4 rr;
            rr.x = a.x + b.x + c.x; rr.y = a.y + b.y + c.y;
            rr.z = a.z + b.z + c.z; rr.w = a.w + b.w + c.w;
            po[i] = rr;
        }
    }
    if (blockIdx.x < N_GRAPHS) {
        int g = blockIdx.x, d = threadIdx.x;
        int lo = lowerBound(batch, N_NODES, g);
        int hi = lowerBound(batch, N_NODES, g + 1);
        float cnt = (float)(hi - lo);
        out_embed[(size_t)g * HID + d] = sums[g * HID + d] / fmaxf(cnt, 1.0f);
    }
}

// ---------------- launcher ----------------
extern "C" void kernel_launch(void* const* d_in, const int* in_sizes, int n_in,
                              void* d_out, int out_size, void* d_ws, size_t ws_size,
                              hipStream_t stream) {
    const float* node_feats = (const float*)d_in[0];
    const int*   edge_index = (const int*)d_in[1];
    const int*   batch_idx  = (const int*)d_in[2];
    const float* W_rel0  = (const float*)d_in[3];
    const float* W_root0 = (const float*)d_in[4];
    const float* b0      = (const float*)d_in[5];
    const float* W_rel1  = (const float*)d_in[6];
    const float* W_root1 = (const float*)d_in[7];
    const float* b1      = (const float*)d_in[8];
    const float* W_rel2  = (const float*)d_in[9];
    const float* W_root2 = (const float*)d_in[10];
    const float* b2      = (const float*)d_in[11];
    const float* W_edge  = (const float*)d_in[12];
    const float* b_edge  = (const float*)d_in[13];

    const int* src = edge_index;
    const int* dst = edge_index + N_EDGES;

    char* ws = (char*)d_ws;
    size_t off = 0;
    auto alloc = [&](size_t bytes) -> char* {
        off = (off + 255) & ~(size_t)255;
        char* p = ws + off;
        off += bytes;
        return p;
    };
    unsigned short* xA    = (unsigned short*)alloc((size_t)N_NODES * HID * 2);  // x2
    unsigned short* xB    = (unsigned short*)alloc((size_t)N_NODES * HID * 2);  // x1 / x3
    unsigned short* Yrel  = (unsigned short*)alloc((size_t)N_NODES * HID * 2);
    unsigned short* Yroot = (unsigned short*)alloc((size_t)N_NODES * HID * 2);
    unsigned short* Wt0   = (unsigned short*)alloc(512 * 512 * 2);
    unsigned short* Wt1   = (unsigned short*)alloc(512 * 256 * 2);
    unsigned short* Wt2   = (unsigned short*)alloc(512 * 256 * 2);
    unsigned short* We2T  = (unsigned short*)alloc(32 * 256 * 2);
    float* P     = (float*)alloc((size_t)N_NODES * 32 * 4);
    int* counts  = (int*)alloc((size_t)N_NODES * 4);
    int* offsets = (int*)alloc((size_t)(N_NODES + 1) * 4);
    int* cur     = (int*)alloc((size_t)N_NODES * 4);
    int* csr     = (int*)alloc((size_t)N_EDGES * 4);
    int* bsum    = (int*)alloc(512 * 4);
    float* sums  = (float*)alloc(N_GRAPHS * HID * 4);

    const int nscan = (N_NODES + 255) / 256; // 391

    // fused prep: weights + We2T + zero counts/sums
    k_makeWtAll<<<dim3(8, 8, 4), 256, 0, stream>>>(W_rel0, W_root0, W_rel1, W_root1,
                                                   W_rel2, W_root2, W_edge,
                                                   Wt0, Wt1, Wt2, We2T, counts, sums);

    // CSR build
    k_hist<<<(N_EDGES + 255) / 256, 256, 0, stream>>>(dst, counts);
    k_scanA<<<nscan, 256, 0, stream>>>(counts, bsum);
    k_scanB<<<1, 256, 0, stream>>>(bsum, nscan);
    k_scanC<<<nscan, 256, 0, stream>>>(counts, bsum, offsets, cur);
    k_fill<<<(N_EDGES + 255) / 256, 256, 0, stream>>>(src, dst, cur, csr);

    const int gemmGrid = ((N_NODES + 127) / 128) * 4; // 3128, %8==0
    const int combGrid = (N_NODES + 7) / 8;           // 12500
    // layer 0 (fp32 A via async DMA staging, BK=64, cvt_pk on read)
    k_gemm0<<<gemmGrid, 256, 0, stream>>>(node_feats, Wt0, Yrel, Yroot, N_NODES);
    k_combine<<<combGrid, 256, 0, stream>>>(Yrel, Yroot, offsets, csr, b0, xB);
    // layer 1
    k_gemm<<<gemmGrid, 256, 0, stream>>>(xB, Wt1, Yrel, Yroot, N_NODES, 256);
    k_combine<<<combGrid, 256, 0, stream>>>(Yrel, Yroot, offsets, csr, b1, xA);
    // layer 2
    k_gemm<<<gemmGrid, 256, 0, stream>>>(xA, Wt2, Yrel, Yroot, N_NODES, 256);
    k_combine<<<combGrid, 256, 0, stream>>>(Yrel, Yroot, offsets, csr, b2, xB);

    // edge proj + pool partials (merged), then edge add + pool finalize (merged)
    float* out_logits = (float*)d_out;
    float* out_embed  = (float*)d_out + (size_t)N_EDGES * NREL;
    k_proj_pool<<<PROJ_BLKS + POOL_BLKS, 256, 0, stream>>>(xB, We2T, batch_idx, P, sums);
    k_edge_add<<<(N_EDGES + 255) / 256, 256, 0, stream>>>(P, src, dst, b_edge, out_logits,
                                                          sums, batch_idx, out_embed);
}